// Round 1
// baseline (262.923 us; speedup 1.0000x reference)
//
#include <hip/hip_runtime.h>
#include <hip/hip_bf16.h>

typedef __attribute__((ext_vector_type(8))) short short8;
typedef __attribute__((ext_vector_type(4))) short short4v;
typedef __attribute__((ext_vector_type(4))) float f32x4;

#define MFMA16(a, b, c) __builtin_amdgcn_mfma_f32_16x16x32_bf16(a, b, c, 0, 0, 0)

// round-to-nearest-even f32 -> bf16 bit pattern
__device__ __forceinline__ short f2bf(float f) {
    union { float f; unsigned u; } v; v.f = f;
    unsigned r = v.u + 0x7fffu + ((v.u >> 16) & 1u);
    return (short)(r >> 16);
}

// ---------------------------------------------------------------------------
// Kernel 1: QKV projection.  C = x @ W^T + b for Wq/Wk/Wv.
//   x: [16384, 256] f32.  Outputs: Qb, Kb row-major bf16 [16384][256],
//   V transposed VTg bf16 [B=4][D=256][T=4096]  (so attention can stage V^T
//   tiles with contiguous global reads and conflict-free b128 LDS writes).
// Block: 64 rows of x, all 768 output cols (12 chunks of 64). 256 thr.
// ---------------------------------------------------------------------------
__global__ __launch_bounds__(256) void qkv_proj(
    const float* __restrict__ x,
    const float* __restrict__ Wq, const float* __restrict__ bq,
    const float* __restrict__ Wk, const float* __restrict__ bk,
    const float* __restrict__ Wv, const float* __restrict__ bv,
    short* __restrict__ Qb, short* __restrict__ Kb, short* __restrict__ VTg)
{
    __shared__ short xs[64 * 264];   // x tile bf16, row stride 264 (pad 8)
    __shared__ short wsS[64 * 264];  // W chunk bf16

    const int tid = threadIdx.x;
    const int wid = tid >> 6;
    const int l   = tid & 63;
    const int l15 = l & 15, lg = l >> 4;
    const int r0  = blockIdx.x * 64;

    // stage x tile: 64x256 f32 is one contiguous region
    {
        const float4* src = (const float4*)(x + (size_t)r0 * 256);
        #pragma unroll
        for (int p = 0; p < 16; ++p) {
            float4 v = src[p * 256 + tid];
            int idx = (p * 256 + tid) * 4;
            int row = idx >> 8, col = idx & 255;
            short4v h = { f2bf(v.x), f2bf(v.y), f2bf(v.z), f2bf(v.w) };
            *(short4v*)&xs[row * 264 + col] = h;
        }
    }
    __syncthreads();

    // A-fragments: fixed for all chunks (full K=256 resident)
    short8 afr[8];
    {
        const int arow = wid * 16 + l15;
        #pragma unroll
        for (int ks = 0; ks < 8; ++ks)
            afr[ks] = *(const short8*)&xs[arow * 264 + ks * 32 + lg * 8];
    }

    const float* Wm[3] = { Wq, Wk, Wv };
    const float* bm[3] = { bq, bk, bv };

    for (int c = 0; c < 12; ++c) {
        const int m   = c >> 2;          // 0=Q 1=K 2=V
        const int wr0 = (c & 3) * 64;    // W row (= output col) base
        __syncthreads();                 // prior chunk's reads of wsS done
        {
            const float4* src = (const float4*)(Wm[m] + (size_t)wr0 * 256);
            #pragma unroll
            for (int p = 0; p < 16; ++p) {
                float4 v = src[p * 256 + tid];
                int idx = (p * 256 + tid) * 4;
                int row = idx >> 8, col = idx & 255;
                short4v h = { f2bf(v.x), f2bf(v.y), f2bf(v.z), f2bf(v.w) };
                *(short4v*)&wsS[row * 264 + col] = h;
            }
        }
        __syncthreads();

        f32x4 acc[4] = {};
        #pragma unroll
        for (int n = 0; n < 4; ++n) {
            const short* kr = &wsS[(n * 16 + l15) * 264 + lg * 8];
            #pragma unroll
            for (int ks = 0; ks < 8; ++ks) {
                short8 bfr = *(const short8*)(kr + ks * 32);
                acc[n] = MFMA16(afr[ks], bfr, acc[n]);
            }
        }

        // epilogue: bias, bf16, store
        const int rowbase = r0 + wid * 16 + (lg << 2);
        #pragma unroll
        for (int n = 0; n < 4; ++n) {
            const int col  = wr0 + n * 16 + l15;
            const float bias = bm[m][col];
            #pragma unroll
            for (int j = 0; j < 4; ++j) {
                const int grow = rowbase + j;
                short hv = f2bf(acc[n][j] + bias);
                if (m == 0)      Qb[(size_t)grow * 256 + col] = hv;
                else if (m == 1) Kb[(size_t)grow * 256 + col] = hv;
                else {
                    int bb = grow >> 12, tt = grow & 4095;
                    VTg[(size_t)bb * (256 * 4096) + (size_t)col * 4096 + tt] = hv;
                }
            }
        }
    }
}

// ---------------------------------------------------------------------------
// Kernel 2: causal flash attention.
//   grid (64 q-tiles, 4 batches), 256 thr = 4 waves x 16 Q-rows.
//   BQ = BK = 64.  Q in regs; K tile + V^T tile in padded LDS; online softmax.
// ---------------------------------------------------------------------------
__global__ __launch_bounds__(256) void attn_fwd(
    const short* __restrict__ Qb, const short* __restrict__ Kb,
    const short* __restrict__ VTg, float* __restrict__ out)
{
    __shared__ short Ks[64 * 264];      // K tile [key][d], stride 264
    __shared__ short Vt[256 * 72];      // V^T tile [d][key], stride 72
    __shared__ short Ps[4][16 * 72];    // per-wave P [qrow][key], stride 72

    const int tid = threadIdx.x;
    const int wid = tid >> 6;
    const int l   = tid & 63;
    const int l15 = l & 15, lg = l >> 4;
    const int b   = blockIdx.y;
    const int qt  = blockIdx.x;

    // Q fragments (row = qt*64 + wid*16 + l15)
    short8 aq[8];
    {
        const short* qrow =
            Qb + ((size_t)(b * 4096 + qt * 64 + wid * 16 + l15)) * 256 + lg * 8;
        #pragma unroll
        for (int ks = 0; ks < 8; ++ks)
            aq[ks] = *(const short8*)(qrow + ks * 32);
    }

    f32x4 o[16] = {};
    float mrow[4] = { -INFINITY, -INFINITY, -INFINITY, -INFINITY };
    float srow[4] = { 0.f, 0.f, 0.f, 0.f };

    for (int kt = 0; kt <= qt; ++kt) {
        __syncthreads();   // previous iteration's LDS reads done

        // stage K tile: 64x256 bf16 contiguous
        {
            const short8* src =
                (const short8*)(Kb + ((size_t)(b * 4096 + kt * 64)) * 256);
            #pragma unroll
            for (int p = 0; p < 8; ++p) {
                int idx8 = p * 256 + tid;
                short8 v = src[idx8];
                int idx = idx8 * 8;
                int row = idx >> 8, col = idx & 255;
                *(short8*)&Ks[row * 264 + col] = v;
            }
        }
        // stage V^T tile from transposed global: [d][key] contiguous along key
        {
            const short* srcV = VTg + (size_t)b * (256 * 4096) + kt * 64;
            const int kc = (tid & 7) * 8;
            #pragma unroll
            for (int p = 0; p < 8; ++p) {
                int d = p * 32 + (tid >> 3);
                short8 v = *(const short8*)(srcV + (size_t)d * 4096 + kc);
                *(short8*)&Vt[d * 72 + kc] = v;
            }
        }
        __syncthreads();

        // S = Q K^T  (wave's 16 rows x 64 keys)
        f32x4 s[4] = {};
        #pragma unroll
        for (int n = 0; n < 4; ++n) {
            const short* kr = &Ks[(n * 16 + l15) * 264 + lg * 8];
            #pragma unroll
            for (int ks = 0; ks < 8; ++ks) {
                short8 bfr = *(const short8*)(kr + ks * 32);
                s[n] = MFMA16(aq[ks], bfr, s[n]);
            }
        }

        // scale + causal mask (diag tile only) + per-lane row max
        float pmax[4] = { -INFINITY, -INFINITY, -INFINITY, -INFINITY };
        const bool diag = (kt == qt);
        #pragma unroll
        for (int n = 0; n < 4; ++n) {
            const int key = kt * 64 + n * 16 + l15;
            #pragma unroll
            for (int j = 0; j < 4; ++j) {
                float v = s[n][j] * 0.0625f;   // 1/sqrt(256)
                if (diag) {
                    int qr = qt * 64 + wid * 16 + lg * 4 + j;
                    if (key > qr) v = -INFINITY;
                }
                s[n][j] = v;
                pmax[j] = fmaxf(pmax[j], v);
            }
        }
        #pragma unroll
        for (int off = 1; off < 16; off <<= 1)
            #pragma unroll
            for (int j = 0; j < 4; ++j)
                pmax[j] = fmaxf(pmax[j], __shfl_xor(pmax[j], off, 16));

        float f[4];
        #pragma unroll
        for (int j = 0; j < 4; ++j) {
            float mn = fmaxf(mrow[j], pmax[j]);
            f[j] = __expf(mrow[j] - mn);   // 0 on first tile (-inf - finite)
            mrow[j] = mn;
            srow[j] *= f[j];
        }

        // P = exp(s - m); partial row sums stay per-lane (reduced in epilogue)
        #pragma unroll
        for (int n = 0; n < 4; ++n)
            #pragma unroll
            for (int j = 0; j < 4; ++j) {
                float p = __expf(s[n][j] - mrow[j]);
                srow[j] += p;
                Ps[wid][(lg * 4 + j) * 72 + n * 16 + l15] = f2bf(p);
            }
        asm volatile("s_waitcnt lgkmcnt(0)" ::: "memory");

        // rescale O
        #pragma unroll
        for (int dt = 0; dt < 16; ++dt)
            #pragma unroll
            for (int j = 0; j < 4; ++j)
                o[dt][j] *= f[j];

        // O += P @ V   (A = P from per-wave LDS, B = V^T tile)
        #pragma unroll
        for (int ks2 = 0; ks2 < 2; ++ks2) {
            short8 pa = *(const short8*)&Ps[wid][l15 * 72 + ks2 * 32 + lg * 8];
            #pragma unroll
            for (int dt = 0; dt < 16; ++dt) {
                short8 bv =
                    *(const short8*)&Vt[(dt * 16 + l15) * 72 + ks2 * 32 + lg * 8];
                o[dt] = MFMA16(pa, bv, o[dt]);
            }
        }
    }

    // epilogue: reduce row sums across the 16-lane groups, normalize, store
    #pragma unroll
    for (int off = 1; off < 16; off <<= 1)
        #pragma unroll
        for (int j = 0; j < 4; ++j)
            srow[j] += __shfl_xor(srow[j], off, 16);
    float rs[4];
    #pragma unroll
    for (int j = 0; j < 4; ++j) rs[j] = 1.f / srow[j];

    const int rowbase = qt * 64 + wid * 16 + lg * 4;
    #pragma unroll
    for (int dt = 0; dt < 16; ++dt) {
        const int col = dt * 16 + l15;
        #pragma unroll
        for (int j = 0; j < 4; ++j)
            out[((size_t)(b * 4096 + rowbase + j)) * 256 + col] = o[dt][j] * rs[j];
    }
}

// ---------------------------------------------------------------------------
extern "C" void kernel_launch(void* const* d_in, const int* in_sizes, int n_in,
                              void* d_out, int out_size, void* d_ws, size_t ws_size,
                              hipStream_t stream) {
    const float* x  = (const float*)d_in[0];
    const float* Wq = (const float*)d_in[1];
    const float* bq = (const float*)d_in[2];
    const float* Wk = (const float*)d_in[3];
    const float* bk = (const float*)d_in[4];
    const float* Wv = (const float*)d_in[5];
    const float* bv = (const float*)d_in[6];

    short* Qb  = (short*)d_ws;                         // 16384*256 bf16 = 8 MB
    short* Kb  = Qb + (size_t)16384 * 256;             // 8 MB
    short* VTg = Kb + (size_t)16384 * 256;             // [4][256][4096] = 8 MB
    float* out = (float*)d_out;

    qkv_proj<<<dim3(256), dim3(256), 0, stream>>>(x, Wq, bq, Wk, bk, Wv, bv,
                                                  Qb, Kb, VTg);
    attn_fwd<<<dim3(64, 4), dim3(256), 0, stream>>>(Qb, Kb, VTg, out);
}

// Round 2
// 201.740 us; speedup vs baseline: 1.3033x; 1.3033x over previous
//
#include <hip/hip_runtime.h>
#include <hip/hip_bf16.h>

typedef __attribute__((ext_vector_type(8))) short short8;
typedef __attribute__((ext_vector_type(4))) short short4v;
typedef __attribute__((ext_vector_type(4))) float f32x4;

#define MFMA16(a, b, c) __builtin_amdgcn_mfma_f32_16x16x32_bf16(a, b, c, 0, 0, 0)

// round-to-nearest-even f32 -> bf16 bit pattern
__device__ __forceinline__ short f2bf(float f) {
    union { float f; unsigned u; } v; v.f = f;
    unsigned r = v.u + 0x7fffu + ((v.u >> 16) & 1u);
    return (short)(r >> 16);
}

// ---------------------------------------------------------------------------
// Kernel 0: convert concatenated [Wq;Wk;Wv] (768x256 f32) to bf16.
// ---------------------------------------------------------------------------
__global__ __launch_bounds__(256) void wconv(
    const float* __restrict__ Wq, const float* __restrict__ Wk,
    const float* __restrict__ Wv, short* __restrict__ Wb)
{
    int e = (blockIdx.x * 256 + threadIdx.x) * 8;   // grid 96 -> 196608 elems
    const float* p = (e < 65536) ? (Wq + e)
                   : (e < 131072) ? (Wk + (e - 65536))
                                  : (Wv + (e - 131072));
    float4 a = *(const float4*)p;
    float4 b = *(const float4*)(p + 4);
    short8 h = { f2bf(a.x), f2bf(a.y), f2bf(a.z), f2bf(a.w),
                 f2bf(b.x), f2bf(b.y), f2bf(b.z), f2bf(b.w) };
    *(short8*)(Wb + e) = h;
}

// ---------------------------------------------------------------------------
// Kernel 1: QKV projection.  C = x @ W^T + b.
// Grid (256 row-tiles, 4 col-groups); each block: 64 rows x 192 cols
// (3 chunks of 64), W prefetched to regs (bf16), x tile staged once.
// Outputs: Qb,Kb row-major bf16 [16384][256]; V transposed VTg [4][256][4096].
// ---------------------------------------------------------------------------
__global__ __launch_bounds__(256) void qkv_proj(
    const float* __restrict__ x, const short* __restrict__ Wb,
    const float* __restrict__ bq, const float* __restrict__ bk,
    const float* __restrict__ bv,
    short* __restrict__ Qb, short* __restrict__ Kb, short* __restrict__ VTg)
{
    __shared__ short xs[64 * 264];   // x tile bf16, row stride 264
    __shared__ short wsS[64 * 264];  // W chunk bf16

    const int tid = threadIdx.x;
    const int wid = tid >> 6;
    const int l   = tid & 63;
    const int l15 = l & 15, lg = l >> 4;
    const int r0  = blockIdx.x * 64;
    const int cg  = blockIdx.y;

    // stage x tile (64x256 f32 contiguous), convert to bf16
    {
        const float4* src = (const float4*)(x + (size_t)r0 * 256);
        #pragma unroll
        for (int p = 0; p < 16; ++p) {
            float4 v = src[p * 256 + tid];
            int idx = (p * 256 + tid) * 4;
            int row = idx >> 8, col = idx & 255;
            short4v h = { f2bf(v.x), f2bf(v.y), f2bf(v.z), f2bf(v.w) };
            *(short4v*)&xs[row * 264 + col] = h;
        }
    }

    // prefetch first W chunk to regs
    short8 wreg[8];
    {
        const short8* wsrc = (const short8*)(Wb + (size_t)(cg * 3) * 64 * 256);
        #pragma unroll
        for (int p = 0; p < 8; ++p) wreg[p] = wsrc[p * 256 + tid];
    }
    __syncthreads();

    // A-fragments (full K=256 resident)
    short8 afr[8];
    {
        const int arow = wid * 16 + l15;
        #pragma unroll
        for (int ks = 0; ks < 8; ++ks)
            afr[ks] = *(const short8*)&xs[arow * 264 + ks * 32 + lg * 8];
    }

    const float* bm[3] = { bq, bk, bv };

    for (int c = 0; c < 3; ++c) {
        const int gc  = cg * 3 + c;
        const int m   = gc >> 2;          // 0=Q 1=K 2=V
        const int wr0 = (gc & 3) * 64;    // output col base within m

        // write prefetched W chunk to LDS
        #pragma unroll
        for (int p = 0; p < 8; ++p) {
            int idx8 = p * 256 + tid;
            int row = idx8 >> 5, col = (idx8 & 31) * 8;
            *(short8*)&wsS[row * 264 + col] = wreg[p];
        }
        __syncthreads();

        // prefetch next chunk
        if (c < 2) {
            const short8* wsrc =
                (const short8*)(Wb + (size_t)(gc + 1) * 64 * 256);
            #pragma unroll
            for (int p = 0; p < 8; ++p) wreg[p] = wsrc[p * 256 + tid];
        }

        f32x4 acc[4] = {};
        #pragma unroll
        for (int n = 0; n < 4; ++n) {
            const short* kr = &wsS[(n * 16 + l15) * 264 + lg * 8];
            #pragma unroll
            for (int ks = 0; ks < 8; ++ks) {
                short8 bfr = *(const short8*)(kr + ks * 32);
                acc[n] = MFMA16(afr[ks], bfr, acc[n]);
            }
        }

        const int rowbase = r0 + wid * 16 + (lg << 2);
        #pragma unroll
        for (int n = 0; n < 4; ++n) {
            const int col   = wr0 + n * 16 + l15;
            const float bias = bm[m][col];
            #pragma unroll
            for (int j = 0; j < 4; ++j) {
                const int grow = rowbase + j;
                short hv = f2bf(acc[n][j] + bias);
                if (m == 0)      Qb[(size_t)grow * 256 + col] = hv;
                else if (m == 1) Kb[(size_t)grow * 256 + col] = hv;
                else {
                    int bb = grow >> 12, tt = grow & 4095;
                    VTg[(size_t)bb * (256 * 4096) + (size_t)col * 4096 + tt] = hv;
                }
            }
        }
        __syncthreads();   // wsS reads done before next write
    }
}

// ---------------------------------------------------------------------------
// Kernel 2: causal flash attention, kt-parity split.
//   grid (64 q-tiles, 4 batches), 512 thr = 8 waves.
//   Wave w: row-group rg = w>>1 (16 Q-rows), parity par = w&1 handles
//   kt = par, par+2, ...  Two K/V LDS buffers staged per super-iter with
//   async reg-staging (T14).  Partial (m,s,o) merged via LDS at epilogue.
// ---------------------------------------------------------------------------
__global__ __launch_bounds__(512) void attn_fwd(
    const short* __restrict__ Qb, const short* __restrict__ Kb,
    const short* __restrict__ VTg, float* __restrict__ out)
{
    __shared__ short Ks[2][64 * 264];   // K tiles [key][d], stride 264
    __shared__ short Vt[2][256 * 72];   // V^T tiles [d][key], stride 72
    __shared__ short Ps[8][16 * 72];    // per-wave P [qrow][key]

    const int tid  = threadIdx.x;
    const int wid  = tid >> 6;
    const int l    = tid & 63;
    const int l15  = l & 15, lg = l >> 4;
    const int rg   = wid >> 1;          // row-group 0..3
    const int par  = wid & 1;           // kt parity
    const int th   = tid & 255;         // staging half-thread id
    const int half = tid >> 8;          // which buffer this thread stages
    const int b    = blockIdx.y;
    const int qt   = blockIdx.x;

    // Q fragments (rows qt*64 + rg*16 + l15)
    short8 aq[8];
    {
        const short* qrow =
            Qb + ((size_t)(b * 4096 + qt * 64 + rg * 16 + l15)) * 256 + lg * 8;
        #pragma unroll
        for (int ks = 0; ks < 8; ++ks)
            aq[ks] = *(const short8*)(qrow + ks * 32);
    }

    const short* KbB  = Kb + (size_t)b * 4096 * 256;
    const short* VTgB = VTg + (size_t)b * (256 * 4096);
    const int    kc   = (th & 7) * 8;

    // prefetch super-iter 0
    short8 kreg[8], vreg[8];
    bool valid;
    {
        int ktX = half;
        valid = (ktX <= qt);
        if (valid) {
            const short8* srcK = (const short8*)(KbB + (size_t)(ktX * 64) * 256);
            #pragma unroll
            for (int p = 0; p < 8; ++p) kreg[p] = srcK[p * 256 + th];
            const short* srcV = VTgB + ktX * 64;
            #pragma unroll
            for (int p = 0; p < 8; ++p) {
                int d = p * 32 + (th >> 3);
                vreg[p] = *(const short8*)(srcV + (size_t)d * 4096 + kc);
            }
        }
    }

    f32x4 o[16] = {};
    float mrow[4] = { -INFINITY, -INFINITY, -INFINITY, -INFINITY };
    float srow[4] = { 0.f, 0.f, 0.f, 0.f };

    const int nsi = (qt >> 1) + 1;
    for (int si = 0; si < nsi; ++si) {
        __syncthreads();   // previous compute's LDS reads done

        // write staged regs (vmcnt for last iter's loads hid under compute)
        if (valid) {
            #pragma unroll
            for (int p = 0; p < 8; ++p) {
                int idx8 = p * 256 + th;
                int row = idx8 >> 5, col = (idx8 & 31) * 8;
                *(short8*)&Ks[half][row * 264 + col] = kreg[p];
            }
            #pragma unroll
            for (int p = 0; p < 8; ++p) {
                int d = p * 32 + (th >> 3);
                *(short8*)&Vt[half][d * 72 + kc] = vreg[p];
            }
        }
        __syncthreads();

        // issue next super-iter's loads (latency hides under compute below)
        if (si + 1 < nsi) {
            int ktX = 2 * (si + 1) + half;
            valid = (ktX <= qt);
            if (valid) {
                const short8* srcK =
                    (const short8*)(KbB + (size_t)(ktX * 64) * 256);
                #pragma unroll
                for (int p = 0; p < 8; ++p) kreg[p] = srcK[p * 256 + th];
                const short* srcV = VTgB + ktX * 64;
                #pragma unroll
                for (int p = 0; p < 8; ++p) {
                    int d = p * 32 + (th >> 3);
                    vreg[p] = *(const short8*)(srcV + (size_t)d * 4096 + kc);
                }
            }
        } else valid = false;

        const int kt = 2 * si + par;
        if (kt > qt) continue;

        // S = Q K^T
        f32x4 s[4] = {};
        #pragma unroll
        for (int n = 0; n < 4; ++n) {
            const short* kr = &Ks[par][(n * 16 + l15) * 264 + lg * 8];
            #pragma unroll
            for (int ks = 0; ks < 8; ++ks) {
                short8 bfr = *(const short8*)(kr + ks * 32);
                s[n] = MFMA16(aq[ks], bfr, s[n]);
            }
        }

        // scale + causal mask (diag tile only) + per-lane row max
        float pmax[4] = { -INFINITY, -INFINITY, -INFINITY, -INFINITY };
        const bool diag = (kt == qt);
        #pragma unroll
        for (int n = 0; n < 4; ++n) {
            const int key = kt * 64 + n * 16 + l15;
            #pragma unroll
            for (int j = 0; j < 4; ++j) {
                float v = s[n][j] * 0.0625f;   // 1/sqrt(256)
                if (diag) {
                    int qr = qt * 64 + rg * 16 + lg * 4 + j;
                    if (key > qr) v = -INFINITY;
                }
                s[n][j] = v;
                pmax[j] = fmaxf(pmax[j], v);
            }
        }
        #pragma unroll
        for (int off = 1; off < 16; off <<= 1)
            #pragma unroll
            for (int j = 0; j < 4; ++j)
                pmax[j] = fmaxf(pmax[j], __shfl_xor(pmax[j], off, 16));

        float f[4];
        #pragma unroll
        for (int j = 0; j < 4; ++j) {
            float mn = fmaxf(mrow[j], pmax[j]);
            f[j] = __expf(mrow[j] - mn);
            mrow[j] = mn;
            srow[j] *= f[j];
        }

        // P = exp(s - m); per-lane partial row sums
        #pragma unroll
        for (int n = 0; n < 4; ++n)
            #pragma unroll
            for (int j = 0; j < 4; ++j) {
                float p = __expf(s[n][j] - mrow[j]);
                srow[j] += p;
                Ps[wid][(lg * 4 + j) * 72 + n * 16 + l15] = f2bf(p);
            }
        asm volatile("s_waitcnt lgkmcnt(0)" ::: "memory");

        // rescale O
        #pragma unroll
        for (int dt = 0; dt < 16; ++dt)
            #pragma unroll
            for (int j = 0; j < 4; ++j)
                o[dt][j] *= f[j];

        // O += P @ V
        #pragma unroll
        for (int ks2 = 0; ks2 < 2; ++ks2) {
            short8 pa = *(const short8*)&Ps[wid][l15 * 72 + ks2 * 32 + lg * 8];
            #pragma unroll
            for (int dt = 0; dt < 16; ++dt) {
                short8 bv =
                    *(const short8*)&Vt[par][(dt * 16 + l15) * 72 + ks2 * 32 + lg * 8];
                o[dt] = MFMA16(pa, bv, o[dt]);
            }
        }
    }

    // reduce row sums across the 16-lane groups
    #pragma unroll
    for (int off = 1; off < 16; off <<= 1)
        #pragma unroll
        for (int j = 0; j < 4; ++j)
            srow[j] += __shfl_xor(srow[j], off, 16);

    // merge parity partials via LDS (reuse staging buffers)
    __syncthreads();
    float* oscr  = (float*)&Ks[0][0];   // [64 rows][256 cols] f32 = 64 KB
    float* msscr = (float*)&Vt[0][0];   // [64 rows][2] f32

    if (par == 1) {
        #pragma unroll
        for (int j = 0; j < 4; ++j)
            if (l15 == 0) {
                int row = rg * 16 + lg * 4 + j;
                msscr[row * 2 + 0] = mrow[j];
                msscr[row * 2 + 1] = srow[j];
            }
        #pragma unroll
        for (int dt = 0; dt < 16; ++dt)
            #pragma unroll
            for (int j = 0; j < 4; ++j)
                oscr[(rg * 16 + lg * 4 + j) * 256 + dt * 16 + l15] = o[dt][j];
    }
    __syncthreads();
    if (par == 0) {
        float f0[4], f1[4], rs[4];
        #pragma unroll
        for (int j = 0; j < 4; ++j) {
            int row = rg * 16 + lg * 4 + j;
            float m1 = msscr[row * 2 + 0], s1 = msscr[row * 2 + 1];
            float mS = fmaxf(mrow[j], m1);
            f0[j] = __expf(mrow[j] - mS);
            f1[j] = __expf(m1 - mS);
            rs[j] = 1.f / (srow[j] * f0[j] + s1 * f1[j]);
        }
        const int rowbase = qt * 64 + rg * 16 + lg * 4;
        #pragma unroll
        for (int dt = 0; dt < 16; ++dt) {
            const int col = dt * 16 + l15;
            #pragma unroll
            for (int j = 0; j < 4; ++j) {
                float o1 = oscr[(rg * 16 + lg * 4 + j) * 256 + col];
                float v  = (o[dt][j] * f0[j] + o1 * f1[j]) * rs[j];
                out[((size_t)(b * 4096 + rowbase + j)) * 256 + col] = v;
            }
        }
    }
}

// ---------------------------------------------------------------------------
extern "C" void kernel_launch(void* const* d_in, const int* in_sizes, int n_in,
                              void* d_out, int out_size, void* d_ws, size_t ws_size,
                              hipStream_t stream) {
    const float* x  = (const float*)d_in[0];
    const float* Wq = (const float*)d_in[1];
    const float* bq = (const float*)d_in[2];
    const float* Wk = (const float*)d_in[3];
    const float* bk = (const float*)d_in[4];
    const float* Wv = (const float*)d_in[5];
    const float* bv = (const float*)d_in[6];

    short* Qb  = (short*)d_ws;                         // 8 MB
    short* Kb  = Qb + (size_t)16384 * 256;             // 8 MB
    short* VTg = Kb + (size_t)16384 * 256;             // 8 MB
    short* Wb  = VTg + (size_t)4 * 256 * 4096;         // 384 KB
    float* out = (float*)d_out;

    wconv<<<dim3(96), dim3(256), 0, stream>>>(Wq, Wk, Wv, Wb);
    qkv_proj<<<dim3(256, 4), dim3(256), 0, stream>>>(x, Wb, bq, bk, bv,
                                                     Qb, Kb, VTg);
    attn_fwd<<<dim3(64, 4), dim3(512), 0, stream>>>(Qb, Kb, VTg, out);
}